// Round 11
// baseline (571.897 us; speedup 1.0000x reference)
//
#include <hip/hip_runtime.h>

typedef unsigned short u16;
typedef unsigned int u32;
typedef __bf16 bf16x8 __attribute__((ext_vector_type(8)));
typedef float f32x4 __attribute__((ext_vector_type(4)));

union U16x8 { uint4 u4; u16 us[8]; };

__device__ __forceinline__ u16 f2bf(float f) {
  u32 u = __builtin_bit_cast(u32, f);
  u = (u + 0x7fffu + ((u >> 16) & 1u)) >> 16;
  return (u16)u;
}
__device__ __forceinline__ float bf2f(u16 h) {
  return __builtin_bit_cast(float, ((u32)h) << 16);
}

// async global->LDS, 16B per lane; LDS dest = wave-uniform base + lane*16 [m97/m104]
__device__ __forceinline__ void gll16(const u16* g, u16* l) {
  __builtin_amdgcn_global_load_lds((const __attribute__((address_space(1))) void*)g,
                                   (__attribute__((address_space(3))) void*)l, 16, 0, 0);
}

// ---------------- all fp32 -> bf16 conversions in one launch ----------------
__global__ __launch_bounds__(256) void cvt_all(const float* __restrict__ x,
                                               const float* __restrict__ WQ,
                                               const float* __restrict__ WK,
                                               const float* __restrict__ WV,
                                               const float* __restrict__ WO,
                                               const float* __restrict__ W1,
                                               const float* __restrict__ W2,
                                               u16* __restrict__ xb,
                                               u16* __restrict__ wqkvb,
                                               u16* __restrict__ wob,
                                               u16* __restrict__ w1b,
                                               u16* __restrict__ w2b) {
  const int S = 1 << 20;
  int i = (blockIdx.x * 256 + threadIdx.x) * 4;
  const float* src;
  u16* dst;
  if (i < 8 * S) { src = x + i; dst = xb + i; }
  else {
    int j = i - 8 * S;
    if (j < 3 * S)      { src = (j < S) ? WQ + j : (j < 2 * S) ? WK + (j - S) : WV + (j - 2 * S);
                          dst = wqkvb + j; }
    else if (j < 4 * S) { src = WO + (j - 3 * S); dst = wob + (j - 3 * S); }
    else if (j < 8 * S) { src = W1 + (j - 4 * S); dst = w1b + (j - 4 * S); }
    else                { src = W2 + (j - 8 * S); dst = w2b + (j - 8 * S); }
  }
  float4 v = *(const float4*)src;
  uint2 o;
  o.x = (u32)f2bf(v.x) | ((u32)f2bf(v.y) << 16);
  o.y = (u32)f2bf(v.z) | ((u32)f2bf(v.w) << 16);
  *(uint2*)dst = o;
}

// ---------------- bf16 MFMA GEMM: C = A @ W^T + bias ----------------
// BMT x 128 tile, BK=64, unpadded 128B LDS rows, global_load_lds staging with
// row&7 XOR chunk swizzle. NBN>0: 1D grid XCD-swizzled. SPLIT=1 (BMT=128 only):
// K halved, kz=0 -> C0 (+bias), kz=1 -> C1 (bf16 partials). QKV=1: N=3072 fused;
// seg0 = Q scaled by 0.125*log2(e), seg1=K, seg2=V transposed.
// BMT=256 (FF1): halves W re-fetch rounds (each W tile serves 256 rows);
// acc 8x4 per wave, ~200 VGPR -> 2 blocks/CU, 64 MFMA/wave per barrier.
template <int RELU, int OUT_BF16, int QKV, int SPLIT, int NBN, int BMT>
__global__ __launch_bounds__(256) void gemm_bt(const u16* __restrict__ A,
                                               const u16* __restrict__ W,
                                               const float* __restrict__ bias0,
                                               void* __restrict__ C0,
                                               int M, int N, int K,
                                               const float* __restrict__ bias1,
                                               void* __restrict__ C1,
                                               const float* __restrict__ bias2,
                                               void* __restrict__ C2) {
  constexpr int NBNC = (NBN > 0) ? NBN : 1;   // avoid div-by-zero in dead branch
  constexpr int MI = BMT / 32;                // A frag tiles per wave (4 or 8)
  __shared__ alignas(16) u16 sA[BMT * 64];
  __shared__ alignas(16) u16 sB[128 * 64];
  const int tid = threadIdx.x;
  int bn, bm, koff = 0, KL = K, kz = 0;
  if (SPLIT) {
    const int id = blockIdx.x;               // 1024 blocks; XCD = id & 7
    const int within = id >> 3;
    const int G = (id & 7) + 8 * (within >> 3);  // (bm,kz) group, 0..127
    bn = (within & 7) * 128;
    bm = (G & 63) * 128;
    kz = G >> 6;
    KL = K >> 1;
    koff = kz * KL;
  } else if (NBN > 0) {
    const int id = blockIdx.x;               // NBN*(M/BMT) blocks
    const int xcd = id & 7;
    const int r = id >> 3;
    bn = (r % NBNC) * 128;
    bm = ((r / NBNC) * 8 + xcd) * BMT;
  } else {
    bn = blockIdx.x * 128;
    bm = blockIdx.y * BMT;
  }
  const int lane = tid & 63, wave = tid >> 6;
  const int wm = (wave >> 1) * (BMT / 2), wn = (wave & 1) * 64;
  const int lr = lane & 15, quad = lane >> 4;
  f32x4 acc[MI][4] = {};

  // staging: per call 8 rows x 8 chunks; source chunk = (lane&7) ^ (row&7)
  const int srow8 = lane >> 3;
  const int sc = ((lane & 7) ^ srow8) * 8;
  const u16* Ap = A + (size_t)(bm + wave * (BMT / 4) + srow8) * K + koff + sc;
  const u16* Wp = W + (size_t)(bn + wave * 32 + srow8) * K + koff + sc;
  u16* sAb = sA + wave * (BMT / 4) * 64;
  u16* sBb = sB + wave * 32 * 64;
  const size_t rK8 = (size_t)8 * K;
  const int fsw = lr & 7;  // fragment-read swizzle key (row&7 == lr&7)

  for (int kt = 0; kt < KL; kt += 64) {
    __syncthreads();
    #pragma unroll
    for (int j = 0; j < BMT / 32; j++)
      gll16(Ap + kt + j * rK8, sAb + j * 8 * 64);
    #pragma unroll
    for (int j = 0; j < 4; j++)
      gll16(Wp + kt + j * rK8, sBb + j * 8 * 64);
    __syncthreads();
    #pragma unroll
    for (int sl = 0; sl < 2; sl++) {
      bf16x8 bfr[4];
      #pragma unroll
      for (int ni = 0; ni < 4; ni++)
        bfr[ni] = *(const bf16x8*)(sB + (wn + ni * 16 + lr) * 64 + ((((sl << 2) | quad) ^ fsw) * 8));
      #pragma unroll
      for (int mh = 0; mh < MI / 4; mh++) {
        bf16x8 af[4];
        #pragma unroll
        for (int m4 = 0; m4 < 4; m4++)
          af[m4] = *(const bf16x8*)(sA + (wm + (mh * 4 + m4) * 16 + lr) * 64 + ((((sl << 2) | quad) ^ fsw) * 8));
        #pragma unroll
        for (int m4 = 0; m4 < 4; m4++)
          #pragma unroll
          for (int ni = 0; ni < 4; ni++)
            acc[mh * 4 + m4][ni] = __builtin_amdgcn_mfma_f32_16x16x32_bf16(af[m4], bfr[ni], acc[mh * 4 + m4][ni], 0, 0, 0);
      }
    }
  }

  // epilogue: C/D layout col=lane&15, row=quad*4+reg [m89/m91]
  const float* bp = bias0;
  void* outp = C0;
  float scale = 1.0f;
  int cb = bn, Nout = N;
  int seg = 0;
  if (QKV) {
    Nout = 1024;
    seg = bn >> 10;
    cb = bn - (seg << 10);
    if (seg == 0) scale = 0.125f * 1.44269504089f;  // 1/sqrt(dk) * log2(e): attn uses exp2
    else if (seg == 1) { bp = bias1; outp = C1; }
    else { bp = bias2; outp = C2; }
  }
  if (SPLIT && kz) outp = C1;

  if (QKV && seg == 2) {
    // V: store transposed. 4 consecutive tokens per lane -> 8B packed stores.
    #pragma unroll
    for (int ni = 0; ni < 4; ni++) {
      const int col = cb + wn + ni * 16 + lr;
      const int hh = col >> 6, dl = col & 63;
      const float bv = bp[col];
      #pragma unroll
      for (int mi = 0; mi < MI; mi++) {
        const int row0 = bm + wm + mi * 16 + quad * 4;
        const int bb = row0 >> 11, tt = row0 & 2047;
        u16 pk[4];
        #pragma unroll
        for (int rg = 0; rg < 4; rg++) pk[rg] = f2bf(acc[mi][ni][rg] + bv);
        uint2 val;
        val.x = (u32)pk[0] | ((u32)pk[1] << 16);
        val.y = (u32)pk[2] | ((u32)pk[3] << 16);
        *(uint2*)(((u16*)outp) + ((size_t)((bb * 16 + hh) * 64 + dl)) * 2048 + tt) = val;
      }
    }
    return;
  }

  #pragma unroll
  for (int ni = 0; ni < 4; ni++) {
    const int col = cb + wn + ni * 16 + lr;
    const float bv = (SPLIT && kz) ? 0.0f : bp[col];
    #pragma unroll
    for (int mi = 0; mi < MI; mi++) {
      #pragma unroll
      for (int rg = 0; rg < 4; rg++) {
        int row = bm + wm + mi * 16 + quad * 4 + rg;
        float v = (acc[mi][ni][rg] + bv) * scale;
        if (RELU) v = fmaxf(v, 0.0f);
        if (OUT_BF16) ((u16*)outp)[(size_t)row * Nout + col] = f2bf(v);
        else          ((float*)outp)[(size_t)row * Nout + col] = v;
      }
    }
  }
}

// ---------------- MFMA flash attention: shared k-sweep, S^T layout ----------------
// Block p handles q-tiles A=31-p and B=p with one k-sweep; K/V staged once.
// S^T = K Q^T via mfma(kf, qf): each lane holds 16 P values for ITS query
// (query=lr, keys=nt*16+quad*4+rg) -> packed b64 P writes (v_perm pairs) and
// register row-sums for the denominator. P = exp2(s) (Q pre-scaled by log2(e)/8);
// mask -1e30 underflows exp2 to exactly 0. P truncated to bf16 (hi16).
constexpr int ALD = 72;  // sP row stride (u16)

__global__ __launch_bounds__(256) void attn_mfma(const u16* __restrict__ qb,
                                                 const u16* __restrict__ kb,
                                                 const u16* __restrict__ vt,
                                                 u16* __restrict__ ctxb, int T) {
  __shared__ alignas(16) u16 sK[64 * 64];
  __shared__ alignas(16) u16 sVt[64 * 64];
  __shared__ alignas(16) u16 sP[4 * 2 * 16 * ALD];
  const int tid = threadIdx.x;
  const int i = blockIdx.x;
  const int g = (i & 7) | (((i >> 7) & 7) << 3);  // all 16 p-blocks of g share i&7 (XCD)
  const int p = (i >> 3) & 15;
  const int h = g >> 2, b = g & 3;
  const size_t base = ((size_t)(b * T)) * 1024 + h * 64;
  const size_t vbase = ((size_t)((b * 16 + h) * 64)) * T;
  const int lane = tid & 63, wave = tid >> 6;
  const int lr = lane & 15, quad = lane >> 4;
  u16* sPA = sP + (wave * 2) * 16 * ALD;
  u16* sPB = sPA + 16 * ALD;

  const int srow = lane >> 3;
  const int sch = ((lane & 7) ^ srow) * 8;
  const int fsw = lr & 7;

  const int qtA = 31 - p, qtB = p;
  const int q0A = qtA * 64 + wave * 16, q0B = qtB * 64 + wave * 16;
  bf16x8 qfA[2], qfB[2];
  #pragma unroll
  for (int sl = 0; sl < 2; sl++) {
    uint4 uA = *(const uint4*)(qb + base + (size_t)(q0A + lr) * 1024 + sl * 32 + quad * 8);
    qfA[sl] = __builtin_bit_cast(bf16x8, uA);
    uint4 uB = *(const uint4*)(qb + base + (size_t)(q0B + lr) * 1024 + sl * 32 + quad * 8);
    qfB[sl] = __builtin_bit_cast(bf16x8, uB);
  }
  f32x4 oA[4] = {}, oB[4] = {};
  float smA[4] = {0, 0, 0, 0}, smB[4] = {0, 0, 0, 0};

  for (int kt = 0; kt <= qtA; kt++) {
    const bool doB = (kt <= qtB);
    __syncthreads();
    #pragma unroll
    for (int j = 0; j < 2; j++) {
      const int rowbase = (wave * 2 + j) * 8;
      const int r = rowbase + srow;
      gll16(kb + base + (size_t)(kt * 64 + r) * 1024 + sch, sK + rowbase * 64);
      gll16(vt + vbase + (size_t)r * T + (size_t)(kt * 64) + sch, sVt + rowbase * 64);
    }
    __syncthreads();

    // S^T = K Q^T (kf as A operand, shared between q-tiles); log2 units.
    f32x4 sa[4] = {}, sb[4] = {};
    #pragma unroll
    for (int sl = 0; sl < 2; sl++) {
      bf16x8 kf[4];
      #pragma unroll
      for (int nt = 0; nt < 4; nt++)
        kf[nt] = *(const bf16x8*)(sK + (nt * 16 + lr) * 64 + ((((sl << 2) | quad) ^ fsw) * 8));
      #pragma unroll
      for (int nt = 0; nt < 4; nt++)
        sa[nt] = __builtin_amdgcn_mfma_f32_16x16x32_bf16(kf[nt], qfA[sl], sa[nt], 0, 0, 0);
      if (doB) {
        #pragma unroll
        for (int nt = 0; nt < 4; nt++)
          sb[nt] = __builtin_amdgcn_mfma_f32_16x16x32_bf16(kf[nt], qfB[sl], sb[nt], 0, 0, 0);
      }
    }

    // causal masks on diagonal tiles: key (nt*16+quad*4+rg) > query (wave*16+lr)
    const int qloc = wave * 16 + lr;
    if (kt == qtA) {
      #pragma unroll
      for (int nt = 0; nt < 4; nt++)
        #pragma unroll
        for (int rg = 0; rg < 4; rg++)
          if (nt * 16 + quad * 4 + rg > qloc) sa[nt][rg] = -1e30f;
    }
    if (doB && kt == qtB) {
      #pragma unroll
      for (int nt = 0; nt < 4; nt++)
        #pragma unroll
        for (int rg = 0; rg < 4; rg++)
          if (nt * 16 + quad * 4 + rg > qloc) sb[nt][rg] = -1e30f;
    }

    // P = exp2(S), v_perm-packed truncated bf16, one b64 write per nt;
    // row-sum accumulated in registers (lane's own query).
    #pragma unroll
    for (int nt = 0; nt < 4; nt++) {
      float e0 = __builtin_amdgcn_exp2f(sa[nt][0]);
      float e1 = __builtin_amdgcn_exp2f(sa[nt][1]);
      float e2 = __builtin_amdgcn_exp2f(sa[nt][2]);
      float e3 = __builtin_amdgcn_exp2f(sa[nt][3]);
      smA[nt] += (e0 + e1) + (e2 + e3);
      uint2 pk;
      pk.x = __builtin_amdgcn_perm(__builtin_bit_cast(u32, e1), __builtin_bit_cast(u32, e0), 0x07060302u);
      pk.y = __builtin_amdgcn_perm(__builtin_bit_cast(u32, e3), __builtin_bit_cast(u32, e2), 0x07060302u);
      *(uint2*)(sPA + lr * ALD + nt * 16 + quad * 4) = pk;
    }
    if (doB) {
      #pragma unroll
      for (int nt = 0; nt < 4; nt++) {
        float e0 = __builtin_amdgcn_exp2f(sb[nt][0]);
        float e1 = __builtin_amdgcn_exp2f(sb[nt][1]);
        float e2 = __builtin_amdgcn_exp2f(sb[nt][2]);
        float e3 = __builtin_amdgcn_exp2f(sb[nt][3]);
        smB[nt] += (e0 + e1) + (e2 + e3);
        uint2 pk;
        pk.x = __builtin_amdgcn_perm(__builtin_bit_cast(u32, e1), __builtin_bit_cast(u32, e0), 0x07060302u);
        pk.y = __builtin_amdgcn_perm(__builtin_bit_cast(u32, e3), __builtin_bit_cast(u32, e2), 0x07060302u);
        *(uint2*)(sPB + lr * ALD + nt * 16 + quad * 4) = pk;
      }
    }
    asm volatile("" ::: "memory");  // wave-private: per-wave DS ordering suffices

    // O += P V  (vf shared between q-tiles)
    #pragma unroll
    for (int sl = 0; sl < 2; sl++) {
      bf16x8 vf[4];
      #pragma unroll
      for (int nt = 0; nt < 4; nt++)
        vf[nt] = *(const bf16x8*)(sVt + (nt * 16 + lr) * 64 + ((((sl << 2) | quad) ^ fsw) * 8));
      bf16x8 pfA = *(const bf16x8*)(sPA + lr * ALD + sl * 32 + quad * 8);
      #pragma unroll
      for (int nt = 0; nt < 4; nt++)
        oA[nt] = __builtin_amdgcn_mfma_f32_16x16x32_bf16(pfA, vf[nt], oA[nt], 0, 0, 0);
      if (doB) {
        bf16x8 pfB = *(const bf16x8*)(sPB + lr * ALD + sl * 32 + quad * 8);
        #pragma unroll
        for (int nt = 0; nt < 4; nt++)
          oB[nt] = __builtin_amdgcn_mfma_f32_16x16x32_bf16(pfB, vf[nt], oB[nt], 0, 0, 0);
      }
    }
  }

  // denominators: lane holds l for query=lr (4 partials); reduce across quads,
  // then shfl to the (quad*4+rg) distribution the C-layout epilogue needs.
  float sumA = (smA[0] + smA[1]) + (smA[2] + smA[3]);
  sumA += __shfl_xor(sumA, 16);
  sumA += __shfl_xor(sumA, 32);
  float sumB = (smB[0] + smB[1]) + (smB[2] + smB[3]);
  sumB += __shfl_xor(sumB, 16);
  sumB += __shfl_xor(sumB, 32);
  float invA[4], invB[4];
  #pragma unroll
  for (int rg = 0; rg < 4; rg++) {
    invA[rg] = 1.0f / __shfl(sumA, quad * 4 + rg);
    invB[rg] = 1.0f / __shfl(sumB, quad * 4 + rg);
  }
  #pragma unroll
  for (int nt = 0; nt < 4; nt++)
    #pragma unroll
    for (int rg = 0; rg < 4; rg++) {
      int qrow = q0A + quad * 4 + rg;
      ctxb[base + (size_t)qrow * 1024 + nt * 16 + lr] = f2bf(oA[nt][rg] * invA[rg]);
    }
  #pragma unroll
  for (int nt = 0; nt < 4; nt++)
    #pragma unroll
    for (int rg = 0; rg < 4; rg++) {
      int qrow = q0B + quad * 4 + rg;
      ctxb[base + (size_t)qrow * 1024 + nt * 16 + lr] = f2bf(oB[nt][rg] * invB[rg]);
    }
}

// ---------------- fused residual + split-K reduce (bf16 partials) + LayerNorm ----------------
// out = LN(a + b + c) * g + be ;  a is fp32 (ABF=0) or bf16 (ABF=1); b,c bf16 partials
template <int ABF>
__global__ __launch_bounds__(256) void ln_kernel(const void* __restrict__ a,
                                                 const u16* __restrict__ b,
                                                 const u16* __restrict__ c,
                                                 const float* __restrict__ g,
                                                 const float* __restrict__ be,
                                                 float* __restrict__ of32,
                                                 u16* __restrict__ obf) {
  const int row = blockIdx.x;
  const int tid = threadIdx.x;
  const size_t base = (size_t)row * 1024;
  const int cc = tid * 4;
  float a0, a1, a2, a3;
  if (ABF) {
    uint2 ua = *(const uint2*)((const u16*)a + base + cc);
    a0 = bf2f(ua.x & 0xffff); a1 = bf2f(ua.x >> 16);
    a2 = bf2f(ua.y & 0xffff); a3 = bf2f(ua.y >> 16);
  } else {
    float4 xa = *(const float4*)((const float*)a + base + cc);
    a0 = xa.x; a1 = xa.y; a2 = xa.z; a3 = xa.w;
  }
  uint2 ub = *(const uint2*)(b + base + cc);
  uint2 uc = *(const uint2*)(c + base + cc);
  float v0 = a0 + bf2f(ub.x & 0xffff) + bf2f(uc.x & 0xffff);
  float v1 = a1 + bf2f(ub.x >> 16)    + bf2f(uc.x >> 16);
  float v2 = a2 + bf2f(ub.y & 0xffff) + bf2f(uc.y & 0xffff);
  float v3 = a3 + bf2f(ub.y >> 16)    + bf2f(uc.y >> 16);
  float s1 = v0 + v1 + v2 + v3;
  float s2 = v0 * v0 + v1 * v1 + v2 * v2 + v3 * v3;
  for (int off = 1; off < 64; off <<= 1) {
    s1 += __shfl_xor(s1, off);
    s2 += __shfl_xor(s2, off);
  }
  __shared__ float red[8];
  int wv = tid >> 6;
  if ((tid & 63) == 0) { red[wv] = s1; red[4 + wv] = s2; }
  __syncthreads();
  s1 = red[0] + red[1] + red[2] + red[3];
  s2 = red[4] + red[5] + red[6] + red[7];
  float mu = s1 * (1.0f / 1024.0f);
  float var = s2 * (1.0f / 1024.0f) - mu * mu;
  float rs = rsqrtf(var + 1e-5f);
  float4 gv = *(const float4*)(g + cc);
  float4 bev = *(const float4*)(be + cc);
  float y0 = (v0 - mu) * rs * gv.x + bev.x;
  float y1 = (v1 - mu) * rs * gv.y + bev.y;
  float y2 = (v2 - mu) * rs * gv.z + bev.z;
  float y3 = (v3 - mu) * rs * gv.w + bev.w;
  if (of32) {
    float4 o = make_float4(y0, y1, y2, y3);
    *(float4*)(of32 + base + cc) = o;
  }
  if (obf) {
    uint2 o;
    o.x = (u32)f2bf(y0) | ((u32)f2bf(y1) << 16);
    o.y = (u32)f2bf(y2) | ((u32)f2bf(y3) << 16);
    *(uint2*)(obf + base + cc) = o;
  }
}

// ---------------- launch ----------------
extern "C" void kernel_launch(void* const* d_in, const int* in_sizes, int n_in,
                              void* d_out, int out_size, void* d_ws, size_t ws_size,
                              hipStream_t stream) {
  const int Mtok = 8192, D = 1024, F = 4096, T = 2048;
  const float* x   = (const float*)d_in[0];
  const float* WQ  = (const float*)d_in[1];
  const float* bQ  = (const float*)d_in[2];
  const float* WK  = (const float*)d_in[3];
  const float* bK  = (const float*)d_in[4];
  const float* WV  = (const float*)d_in[5];
  const float* bV  = (const float*)d_in[6];
  const float* WO  = (const float*)d_in[7];
  const float* bO  = (const float*)d_in[8];
  const float* W1  = (const float*)d_in[9];
  const float* b1  = (const float*)d_in[10];
  const float* W2  = (const float*)d_in[11];
  const float* b2  = (const float*)d_in[12];
  const float* g1  = (const float*)d_in[13];
  const float* be1 = (const float*)d_in[14];
  const float* g2  = (const float*)d_in[15];
  const float* be2 = (const float*)d_in[16];

  char* ws = (char*)d_ws;
  const size_t MB = 1024 * 1024;
  u16*  xb     = (u16*)(ws + 0);          // 16 MB (live until ln1)
  u16*  wqkvb  = (u16*)(ws + 16 * MB);    // 6 MB  (dead after QKV)
  u16*  wob    = (u16*)(ws + 22 * MB);    // 2 MB  (dead after WO)
  u16*  w1b    = (u16*)(ws + 24 * MB);    // 8 MB  (dead after FF1)
  u16*  w2b    = (u16*)(ws + 32 * MB);    // 8 MB  (dead after FF2)
  u16*  qb     = (u16*)(ws + 40 * MB);    // 16 MB (dead after attn)
  u16*  kb     = (u16*)(ws + 56 * MB);    // 16 MB (dead after attn)
  u16*  vtb    = (u16*)(ws + 72 * MB);    // 16 MB, written transposed by QKV (dead after attn)
  u16*  ctxb   = (u16*)(ws + 88 * MB);    // 16 MB (dead after WO)
  u16*  wp0    = (u16*)(ws + 104 * MB);   // 16 MB bf16 partial (dead after ln1)
  u16*  wp1    = (u16*)(ws + 120 * MB);   // 16 MB bf16 partial (dead after ln1)
  u16*  h1b    = (u16*)(ws + 136 * MB);   // 16 MB bf16 LN1 output (live until ln2)
  u16*  ff1b   = (u16*)(ws + 40 * MB);    // 64 MB over qb..ctxb (dead after FF2)
  u16*  fp0    = (u16*)(ws + 152 * MB);   // 16 MB bf16 partial
  u16*  fp1    = (u16*)(ws + 168 * MB);   // 16 MB bf16 partial
  float* out   = (float*)d_out;

  dim3 blk(256);
  cvt_all<<<(20 << 20) / 1024, blk, 0, stream>>>(x, WQ, WK, WV, WO, W1, W2,
                                                 xb, wqkvb, wob, w1b, w2b);

  // fused QKV (N=3072): seg0=Q scaled log2(e)/8, seg1=K, seg2=V stored transposed
  gemm_bt<0, 1, 1, 0, 24, 128><<<dim3(1536), blk, 0, stream>>>(xb, wqkvb, bQ, qb, Mtok, 3072, D,
                                                               bK, kb, bV, vtb);
  attn_mfma<<<dim3(1024), blk, 0, stream>>>(qb, kb, vtb, ctxb, T);

  // WO projection, split-K=2 -> bf16 partials wp0/wp1; ln1 reduces (bf16 residual xb)
  gemm_bt<0, 1, 0, 1, 0, 128><<<dim3(1024), blk, 0, stream>>>(ctxb, wob, bO, wp0, Mtok, D, D,
                                                              nullptr, wp1, nullptr, nullptr);
  ln_kernel<1><<<Mtok, blk, 0, stream>>>(xb, wp0, wp1, g1, be1, nullptr, h1b);

  // FF1: BM=256 tile (halves W1 re-fetch), grid 32x32 -> 1024 blocks XCD-swizzled
  gemm_bt<1, 1, 0, 0, 32, 256><<<dim3(1024), blk, 0, stream>>>(h1b, w1b, b1, ff1b, Mtok, F, D,
                                                               nullptr, nullptr, nullptr, nullptr);
  // FF2, split-K=2 -> bf16 partials fp0/fp1; ln2 reduces (bf16 residual h1b)
  gemm_bt<0, 1, 0, 1, 0, 128><<<dim3(1024), blk, 0, stream>>>(ff1b, w2b, b2, fp0, Mtok, D, F,
                                                              nullptr, fp1, nullptr, nullptr);
  ln_kernel<1><<<Mtok, blk, 0, stream>>>(h1b, fp0, fp1, g2, be2, out, (u16*)nullptr);
}